// Round 5
// baseline (131.574 us; speedup 1.0000x reference)
//
#include <hip/hip_runtime.h>

// Edge detector stencil, reference: _get_edges with NTR=4, DTR=0.0, DELTA=3.
// Input  x: [16, 3, 512, 512] f32  -> 48 planes of 512x512.
// Output  : [16, 24, 512, 512] f32 = [48, 8, 512, 512] flat.
// 4 pixels per thread along w; DENSE float4 stores (lane i -> i*16B, 1KB/wave
// per instruction). Plain (L2-writeback) stores, not nontemporal: round 3
// showed NT bypasses L2 write-combining (exact 2x WRITE_SIZE on half-dense
// stores); fill kernel's plain stores sustain 6.85 TB/s vs our NT 5.46.
// FETCH_SIZE measured ~1x input even unswizzled (L3 dedups halos) -> no
// swizzle, no read-side work needed.

#define IMG_H 512
#define IMG_W 512

typedef float float4v __attribute__((ext_vector_type(4)));

__device__ __forceinline__ void edge_core(
    float pcc, float pmm, float pm0, float pmp,
    float p0m, float p0p, float ppm, float pp0, float ppp,
    float p0mm, float pmm0, float pmmmm, float pppmm,
    float o[8])
{
    float d10   = pm0 - pcc;
    float dn10  = pp0 - pcc;
    float d01   = p0m - pcc;
    float dn01  = p0p - pcc;
    float d11   = pmm - pcc;
    float dnn11 = ppp - pcc;
    float dn11  = ppm - pcc;
    float d1n1  = pmp - pcc;

    float a10 = fabsf(d10),  an10  = fabsf(dn10);
    float a01 = fabsf(d01),  an01  = fabsf(dn01);
    float a11 = fabsf(d11),  ann11 = fabsf(dnn11);
    float an11 = fabsf(dn11), a1n1 = fabsf(d1n1);

    int c10 = (int)(a10 > a01) + (int)(a10 > an01) + (int)(a10 > an10)
            + 2 * (int)(a10 > fabsf(pmm - pm0))
            + (int)(a10 > fabsf(pmp - pm0));

    int c01 = (int)(a01 > a10) + (int)(a01 > an10) + (int)(a01 > an01)
            + (int)(a01 > fabsf(pmm - p0m))
            + (int)(a01 > fabsf(ppm - p0m))
            + (int)(a01 > fabsf(p0mm - p0m));

    int c11 = (int)(a11 > an11) + (int)(a11 > a1n1) + (int)(a11 > ann11)
            + (int)(a11 > fabsf(p0mm - pmm))
            + (int)(a11 > fabsf(pmm0 - pmm))
            + (int)(a11 > fabsf(pmmmm - pmm));

    int cn11 = (int)(an11 > a11) + (int)(an11 > a1n1) + (int)(an11 > ann11)
             + (int)(an11 > fabsf(p0mm - ppm))
             + 2 * (int)(an11 > fabsf(pppmm - ppm));

    o[0] = (c10 > 4 && d10 > 0.f) ? 1.f : 0.f;
    o[1] = (c10 > 4 && d10 < 0.f) ? 1.f : 0.f;
    o[2] = (c01 > 4 && d01 > 0.f) ? 1.f : 0.f;
    o[3] = (c01 > 4 && d01 < 0.f) ? 1.f : 0.f;
    o[4] = (c11 > 4 && d11 > 0.f) ? 1.f : 0.f;
    o[5] = (c11 > 4 && d11 < 0.f) ? 1.f : 0.f;
    o[6] = (cn11 > 4 && dn11 > 0.f) ? 1.f : 0.f;
    o[7] = (cn11 > 4 && dn11 < 0.f) ? 1.f : 0.f;
}

__global__ __launch_bounds__(256) void edge_kernel(const float* __restrict__ in,
                                                   float* __restrict__ out,
                                                   int nimg) {
    int idx = blockIdx.x * blockDim.x + threadIdx.x;
    int wq = idx & (IMG_W / 4 - 1);      // 0..127
    int h = (idx >> 7) & (IMG_H - 1);
    int n = idx >> 16;
    if (n >= nimg) return;
    int w0 = wq * 4;

    const float* img = in + (size_t)n * IMG_H * IMG_W;

    float4v ov[8];

    bool interior = (h >= 2) & (h <= IMG_H - 3) & (w0 >= 4) & (w0 <= IMG_W - 8);

    if (interior) {
        // Window loads: rows h-2..h+2, contiguous spans.
        const float* rowm2 = img + (h - 2) * IMG_W + w0;
        const float* rowm1 = img + (h - 1) * IMG_W + w0;
        const float* row0  = img + h * IMG_W + w0;
        const float* rowp1 = img + (h + 1) * IMG_W + w0;
        const float* rowp2 = img + (h + 2) * IMG_W + w0;

        float rm2[6], rm1[6], r0[7], rp1[6], rp2[4];
#pragma unroll
        for (int j = 0; j < 6; ++j) rm2[j] = rowm2[j - 2];   // cols w0-2..w0+3
#pragma unroll
        for (int j = 0; j < 6; ++j) rm1[j] = rowm1[j - 1];   // cols w0-1..w0+4
#pragma unroll
        for (int j = 0; j < 7; ++j) r0[j]  = row0[j - 2];    // cols w0-2..w0+4
#pragma unroll
        for (int j = 0; j < 6; ++j) rp1[j] = rowp1[j - 1];   // cols w0-1..w0+4
#pragma unroll
        for (int j = 0; j < 4; ++j) rp2[j] = rowp2[j - 2];   // cols w0-2..w0+1

#pragma unroll
        for (int i = 0; i < 4; ++i) {
            float o[8];
            edge_core(r0[i + 2],            // pcc
                      rm1[i], rm1[i + 1], rm1[i + 2],
                      r0[i + 1], r0[i + 3],
                      rp1[i], rp1[i + 1], rp1[i + 2],
                      r0[i],                // p0mm (w-2)
                      rm2[i + 2],           // pmm0 (h-2, w)
                      rm2[i],               // pmmmm (h-2, w-2)
                      rp2[i],               // pppmm (h+2, w-2)
                      o);
#pragma unroll
            for (int k = 0; k < 8; ++k) ov[k][i] = o[k];
        }
    } else {
        auto ld = [&](int hh, int ww) -> float {
            bool ib = (hh >= 0) & (hh < IMG_H) & (ww >= 0) & (ww < IMG_W);
            int hc = min(max(hh, 0), IMG_H - 1);
            int wc = min(max(ww, 0), IMG_W - 1);
            float v = img[hc * IMG_W + wc];
            return ib ? v : 1.0f;
        };
#pragma unroll
        for (int i = 0; i < 4; ++i) {
            int w = w0 + i;
            float o[8];
            edge_core(ld(h, w),
                      ld(h - 1, w - 1), ld(h - 1, w), ld(h - 1, w + 1),
                      ld(h, w - 1), ld(h, w + 1),
                      ld(h + 1, w - 1), ld(h + 1, w), ld(h + 1, w + 1),
                      ld(h, w - 2),
                      ld(h - 2, w),
                      ld(h - 2, w - 2),
                      ld(h + 2, w - 2),
                      o);
            // Boundary gating
            bool hge2 = h >= 2, hlt = h < IMG_H - 2;
            bool wge2 = w >= 2, wlt = w < IMG_W - 2;
            ov[0][i] = (hge2)         ? o[0] : 0.f;
            ov[1][i] = (hlt)          ? o[1] : 0.f;
            ov[2][i] = (wge2)         ? o[2] : 0.f;
            ov[3][i] = (wlt)          ? o[3] : 0.f;
            ov[4][i] = (hge2 && wge2) ? o[4] : 0.f;
            ov[5][i] = (hlt && wlt)   ? o[5] : 0.f;
            ov[6][i] = (hlt && wge2)  ? o[6] : 0.f;
            ov[7][i] = (hge2 && wlt)  ? o[7] : 0.f;
        }
    }

    const size_t cs = (size_t)IMG_H * IMG_W;
    float* obase = out + ((size_t)n * 8) * cs + (size_t)h * IMG_W + w0;
#pragma unroll
    for (int k = 0; k < 8; ++k) {
        *(float4v*)(obase + (size_t)k * cs) = ov[k];
    }
}

extern "C" void kernel_launch(void* const* d_in, const int* in_sizes, int n_in,
                              void* d_out, int out_size, void* d_ws, size_t ws_size,
                              hipStream_t stream) {
    const float* x = (const float*)d_in[0];
    float* out = (float*)d_out;
    int nimg = in_sizes[0] / (IMG_H * IMG_W);            // 48
    long long total = (long long)nimg * IMG_H * (IMG_W / 4);  // threads
    int block = 256;
    int grid = (int)((total + block - 1) / block);
    edge_kernel<<<grid, block, 0, stream>>>(x, out, nimg);
}

// Round 6
// 82.780 us; speedup vs baseline: 1.5894x; 1.5894x over previous
//
#include <hip/hip_runtime.h>

// Edge detector stencil, reference: _get_edges with NTR=4, DTR=0.0, DELTA=3.
// Input  x: [16, 3, 512, 512] f32  -> 48 planes of 512x512.
// Output  : [16, 24, 512, 512] f32 = [48, 8, 512, 512] flat.
//
// Settled by rounds 2-5:
//  - dense float4 NONTEMPORAL stores (lane i -> i*16B, 1KB/wave/instr).
//    NT strided = 2x write amplification (r3); plain stores = L2 thrash (r5).
//  - 4 px/thread, 1 row/thread, no XCD swizzle (FETCH already 1x, r3/r4).
// This round: SINGLE uniform path (no interior/else divergence — previously
// every wave ran BOTH paths since lane0/lane63 are always w-boundary).
// Rows via clamped pointers + valid flags; w-halo via 11 clamped edge
// scalars with select, mids as aligned float4 loads.

#define IMG_H 512
#define IMG_W 512

typedef float float4v __attribute__((ext_vector_type(4)));
typedef float float2v __attribute__((ext_vector_type(2)));

__device__ __forceinline__ void edge_core(
    float pcc, float pmm, float pm0, float pmp,
    float p0m, float p0p, float ppm, float pp0, float ppp,
    float p0mm, float pmm0, float pmmmm, float pppmm,
    float o[8])
{
    float d10   = pm0 - pcc;
    float dn10  = pp0 - pcc;
    float d01   = p0m - pcc;
    float dn01  = p0p - pcc;
    float d11   = pmm - pcc;
    float dnn11 = ppp - pcc;
    float dn11  = ppm - pcc;
    float d1n1  = pmp - pcc;

    float a10 = fabsf(d10),  an10  = fabsf(dn10);
    float a01 = fabsf(d01),  an01  = fabsf(dn01);
    float a11 = fabsf(d11),  ann11 = fabsf(dnn11);
    float an11 = fabsf(dn11), a1n1 = fabsf(d1n1);

    int c10 = (int)(a10 > a01) + (int)(a10 > an01) + (int)(a10 > an10)
            + 2 * (int)(a10 > fabsf(pmm - pm0))
            + (int)(a10 > fabsf(pmp - pm0));

    int c01 = (int)(a01 > a10) + (int)(a01 > an10) + (int)(a01 > an01)
            + (int)(a01 > fabsf(pmm - p0m))
            + (int)(a01 > fabsf(ppm - p0m))
            + (int)(a01 > fabsf(p0mm - p0m));

    int c11 = (int)(a11 > an11) + (int)(a11 > a1n1) + (int)(a11 > ann11)
            + (int)(a11 > fabsf(p0mm - pmm))
            + (int)(a11 > fabsf(pmm0 - pmm))
            + (int)(a11 > fabsf(pmmmm - pmm));

    int cn11 = (int)(an11 > a11) + (int)(an11 > a1n1) + (int)(an11 > ann11)
             + (int)(an11 > fabsf(p0mm - ppm))
             + 2 * (int)(an11 > fabsf(pppmm - ppm));

    o[0] = (c10 > 4 && d10 > 0.f) ? 1.f : 0.f;
    o[1] = (c10 > 4 && d10 < 0.f) ? 1.f : 0.f;
    o[2] = (c01 > 4 && d01 > 0.f) ? 1.f : 0.f;
    o[3] = (c01 > 4 && d01 < 0.f) ? 1.f : 0.f;
    o[4] = (c11 > 4 && d11 > 0.f) ? 1.f : 0.f;
    o[5] = (c11 > 4 && d11 < 0.f) ? 1.f : 0.f;
    o[6] = (cn11 > 4 && dn11 > 0.f) ? 1.f : 0.f;
    o[7] = (cn11 > 4 && dn11 < 0.f) ? 1.f : 0.f;
}

__global__ __launch_bounds__(256) void edge_kernel(const float* __restrict__ in,
                                                   float* __restrict__ out,
                                                   int nimg) {
    int idx = blockIdx.x * blockDim.x + threadIdx.x;
    int wq = idx & (IMG_W / 4 - 1);      // 0..127
    int h = (idx >> 7) & (IMG_H - 1);
    int n = idx >> 16;
    if (n >= nimg) return;
    int w0 = wq * 4;

    const float* img = in + (size_t)n * IMG_H * IMG_W;

    // Clamped row pointers + validity flags (uniform, no branch).
    const float* rM2 = img + max(h - 2, 0) * IMG_W;
    const float* rM1 = img + max(h - 1, 0) * IMG_W;
    const float* R0  = img + h * IMG_W;
    const float* rP1 = img + min(h + 1, IMG_H - 1) * IMG_W;
    const float* rP2 = img + min(h + 2, IMG_H - 1) * IMG_W;

    bool vm2 = (h >= 2), vm1 = (h >= 1);
    bool vp1 = (h <= IMG_H - 2), vp2 = (h <= IMG_H - 3);
    bool vl = (w0 != 0);              // cols w0-1, w0-2 in-range
    bool vr = (w0 != IMG_W - 4);      // col  w0+4 in-range
    int cl2 = max(w0 - 2, 0);
    int cl1 = max(w0 - 1, 0);
    int cr4 = min(w0 + 4, IMG_W - 1);

    // Aligned mid loads (cols w0..w0+3 always valid).
    float4v m_m2 = *(const float4v*)(rM2 + w0);
    float4v m_m1 = *(const float4v*)(rM1 + w0);
    float4v m_0  = *(const float4v*)(R0  + w0);
    float4v m_p1 = *(const float4v*)(rP1 + w0);
    float2v m_p2 = *(const float2v*)(rP2 + w0);

    // Span arrays (same indexing as round-2 interior path).
    float rm2[6], rm1[6], r0[7], rp1[6], rp2[4];

    rm2[0] = (vm2 && vl) ? rM2[cl2] : 1.0f;          // w0-2
    rm2[1] = (vm2 && vl) ? rM2[cl1] : 1.0f;          // w0-1
#pragma unroll
    for (int j = 0; j < 4; ++j) rm2[j + 2] = vm2 ? m_m2[j] : 1.0f;

    rm1[0] = (vm1 && vl) ? rM1[cl1] : 1.0f;          // w0-1
#pragma unroll
    for (int j = 0; j < 4; ++j) rm1[j + 1] = vm1 ? m_m1[j] : 1.0f;
    rm1[5] = (vm1 && vr) ? rM1[cr4] : 1.0f;          // w0+4

    r0[0] = vl ? R0[cl2] : 1.0f;                     // w0-2
    r0[1] = vl ? R0[cl1] : 1.0f;                     // w0-1
#pragma unroll
    for (int j = 0; j < 4; ++j) r0[j + 2] = m_0[j];
    r0[6] = vr ? R0[cr4] : 1.0f;                     // w0+4

    rp1[0] = (vp1 && vl) ? rP1[cl1] : 1.0f;          // w0-1
#pragma unroll
    for (int j = 0; j < 4; ++j) rp1[j + 1] = vp1 ? m_p1[j] : 1.0f;
    rp1[5] = (vp1 && vr) ? rP1[cr4] : 1.0f;          // w0+4

    rp2[0] = (vp2 && vl) ? rP2[cl2] : 1.0f;          // w0-2
    rp2[1] = (vp2 && vl) ? rP2[cl1] : 1.0f;          // w0-1
    rp2[2] = vp2 ? m_p2[0] : 1.0f;                   // w0
    rp2[3] = vp2 ? m_p2[1] : 1.0f;                   // w0+1

    float4v ov[8];
    bool hge2 = (h >= 2), hlt = (h < IMG_H - 2);

#pragma unroll
    for (int i = 0; i < 4; ++i) {
        float o[8];
        edge_core(r0[i + 2],                         // pcc
                  rm1[i], rm1[i + 1], rm1[i + 2],    // pmm, pm0, pmp
                  r0[i + 1], r0[i + 3],              // p0m, p0p
                  rp1[i], rp1[i + 1], rp1[i + 2],    // ppm, pp0, ppp
                  r0[i],                             // p0mm  (w-2)
                  rm2[i + 2],                        // pmm0  (h-2, w)
                  rm2[i],                            // pmmmm (h-2, w-2)
                  rp2[i],                            // pppmm (h+2, w-2)
                  o);
        int w = w0 + i;
        bool wge2 = (w >= 2), wlt = (w < IMG_W - 2);
        ov[0][i] = hge2           ? o[0] : 0.f;
        ov[1][i] = hlt            ? o[1] : 0.f;
        ov[2][i] = wge2           ? o[2] : 0.f;
        ov[3][i] = wlt            ? o[3] : 0.f;
        ov[4][i] = (hge2 && wge2) ? o[4] : 0.f;
        ov[5][i] = (hlt && wlt)   ? o[5] : 0.f;
        ov[6][i] = (hlt && wge2)  ? o[6] : 0.f;
        ov[7][i] = (hge2 && wlt)  ? o[7] : 0.f;
    }

    const size_t cs = (size_t)IMG_H * IMG_W;
    float* obase = out + ((size_t)n * 8) * cs + (size_t)h * IMG_W + w0;
#pragma unroll
    for (int k = 0; k < 8; ++k) {
        __builtin_nontemporal_store(ov[k], (float4v*)(obase + (size_t)k * cs));
    }
}

extern "C" void kernel_launch(void* const* d_in, const int* in_sizes, int n_in,
                              void* d_out, int out_size, void* d_ws, size_t ws_size,
                              hipStream_t stream) {
    const float* x = (const float*)d_in[0];
    float* out = (float*)d_out;
    int nimg = in_sizes[0] / (IMG_H * IMG_W);            // 48
    long long total = (long long)nimg * IMG_H * (IMG_W / 4);  // threads
    int block = 256;
    int grid = (int)((total + block - 1) / block);
    edge_kernel<<<grid, block, 0, stream>>>(x, out, nimg);
}

// Round 7
// 82.301 us; speedup vs baseline: 1.5987x; 1.0058x over previous
//
#include <hip/hip_runtime.h>

// Edge detector stencil, reference: _get_edges with NTR=4, DTR=0.0, DELTA=3.
// Input  x: [16, 3, 512, 512] f32  -> 48 planes of 512x512.
// Output  : [16, 24, 512, 512] f32 = [48, 8, 512, 512] flat.
//
// Settled (r2-r6): dense float4 NT stores; 4 px/thread; no swizzle; uniform
// (branchless) halo path. r6 == r2 == 83us despite very different instr mix
// -> memory-system bound, not issue-bound.
// This round: LDS-staged write phase. Block = 2 full rows of one plane
// (256 thr x 4 px). Compute as r6, stage ov[8] through LDS in two 16KB
// phases; in the write phase EACH WAVE OWNS ONE PLANE and issues 4
// back-to-back dense 1KB NT stores = 4KB contiguous run per stream,
// instead of every wave round-robining all 8 planes at 1KB granularity.
// Tests the HBM page-locality theory for the 5.47 vs ~6.5 TB/s gap.

#define IMG_H 512
#define IMG_W 512

typedef float float4v __attribute__((ext_vector_type(4)));
typedef float float2v __attribute__((ext_vector_type(2)));

__device__ __forceinline__ void edge_core(
    float pcc, float pmm, float pm0, float pmp,
    float p0m, float p0p, float ppm, float pp0, float ppp,
    float p0mm, float pmm0, float pmmmm, float pppmm,
    float o[8])
{
    float d10   = pm0 - pcc;
    float dn10  = pp0 - pcc;
    float d01   = p0m - pcc;
    float dn01  = p0p - pcc;
    float d11   = pmm - pcc;
    float dnn11 = ppp - pcc;
    float dn11  = ppm - pcc;
    float d1n1  = pmp - pcc;

    float a10 = fabsf(d10),  an10  = fabsf(dn10);
    float a01 = fabsf(d01),  an01  = fabsf(dn01);
    float a11 = fabsf(d11),  ann11 = fabsf(dnn11);
    float an11 = fabsf(dn11), a1n1 = fabsf(d1n1);

    int c10 = (int)(a10 > a01) + (int)(a10 > an01) + (int)(a10 > an10)
            + 2 * (int)(a10 > fabsf(pmm - pm0))
            + (int)(a10 > fabsf(pmp - pm0));

    int c01 = (int)(a01 > a10) + (int)(a01 > an10) + (int)(a01 > an01)
            + (int)(a01 > fabsf(pmm - p0m))
            + (int)(a01 > fabsf(ppm - p0m))
            + (int)(a01 > fabsf(p0mm - p0m));

    int c11 = (int)(a11 > an11) + (int)(a11 > a1n1) + (int)(a11 > ann11)
            + (int)(a11 > fabsf(p0mm - pmm))
            + (int)(a11 > fabsf(pmm0 - pmm))
            + (int)(a11 > fabsf(pmmmm - pmm));

    int cn11 = (int)(an11 > a11) + (int)(an11 > a1n1) + (int)(an11 > ann11)
             + (int)(an11 > fabsf(p0mm - ppm))
             + 2 * (int)(an11 > fabsf(pppmm - ppm));

    o[0] = (c10 > 4 && d10 > 0.f) ? 1.f : 0.f;
    o[1] = (c10 > 4 && d10 < 0.f) ? 1.f : 0.f;
    o[2] = (c01 > 4 && d01 > 0.f) ? 1.f : 0.f;
    o[3] = (c01 > 4 && d01 < 0.f) ? 1.f : 0.f;
    o[4] = (c11 > 4 && d11 > 0.f) ? 1.f : 0.f;
    o[5] = (c11 > 4 && d11 < 0.f) ? 1.f : 0.f;
    o[6] = (cn11 > 4 && dn11 > 0.f) ? 1.f : 0.f;
    o[7] = (cn11 > 4 && dn11 < 0.f) ? 1.f : 0.f;
}

__global__ __launch_bounds__(256) void edge_kernel(const float* __restrict__ in,
                                                   float* __restrict__ out) {
    // Block = plane n, rows h0..h0+1 (exact grid: 48 * 256 blocks).
    int bid = blockIdx.x;
    int n   = bid >> 8;              // 0..47
    int h0  = (bid & 255) * 2;       // 0..510
    int tid = threadIdx.x;
    int h   = h0 + (tid >> 7);       // this thread's row
    int w0  = (tid & 127) * 4;       // this thread's 4-px group

    const float* img = in + (size_t)n * IMG_H * IMG_W;

    // ---- compute phase (identical structure to round 6) ----
    const float* rM2 = img + max(h - 2, 0) * IMG_W;
    const float* rM1 = img + max(h - 1, 0) * IMG_W;
    const float* R0  = img + h * IMG_W;
    const float* rP1 = img + min(h + 1, IMG_H - 1) * IMG_W;
    const float* rP2 = img + min(h + 2, IMG_H - 1) * IMG_W;

    bool vm2 = (h >= 2), vm1 = (h >= 1);
    bool vp1 = (h <= IMG_H - 2), vp2 = (h <= IMG_H - 3);
    bool vl = (w0 != 0);
    bool vr = (w0 != IMG_W - 4);
    int cl2 = max(w0 - 2, 0);
    int cl1 = max(w0 - 1, 0);
    int cr4 = min(w0 + 4, IMG_W - 1);

    float4v m_m2 = *(const float4v*)(rM2 + w0);
    float4v m_m1 = *(const float4v*)(rM1 + w0);
    float4v m_0  = *(const float4v*)(R0  + w0);
    float4v m_p1 = *(const float4v*)(rP1 + w0);
    float2v m_p2 = *(const float2v*)(rP2 + w0);

    float rm2[6], rm1[6], r0[7], rp1[6], rp2[4];

    rm2[0] = (vm2 && vl) ? rM2[cl2] : 1.0f;
    rm2[1] = (vm2 && vl) ? rM2[cl1] : 1.0f;
#pragma unroll
    for (int j = 0; j < 4; ++j) rm2[j + 2] = vm2 ? m_m2[j] : 1.0f;

    rm1[0] = (vm1 && vl) ? rM1[cl1] : 1.0f;
#pragma unroll
    for (int j = 0; j < 4; ++j) rm1[j + 1] = vm1 ? m_m1[j] : 1.0f;
    rm1[5] = (vm1 && vr) ? rM1[cr4] : 1.0f;

    r0[0] = vl ? R0[cl2] : 1.0f;
    r0[1] = vl ? R0[cl1] : 1.0f;
#pragma unroll
    for (int j = 0; j < 4; ++j) r0[j + 2] = m_0[j];
    r0[6] = vr ? R0[cr4] : 1.0f;

    rp1[0] = (vp1 && vl) ? rP1[cl1] : 1.0f;
#pragma unroll
    for (int j = 0; j < 4; ++j) rp1[j + 1] = vp1 ? m_p1[j] : 1.0f;
    rp1[5] = (vp1 && vr) ? rP1[cr4] : 1.0f;

    rp2[0] = (vp2 && vl) ? rP2[cl2] : 1.0f;
    rp2[1] = (vp2 && vl) ? rP2[cl1] : 1.0f;
    rp2[2] = vp2 ? m_p2[0] : 1.0f;
    rp2[3] = vp2 ? m_p2[1] : 1.0f;

    float4v ov[8];
    bool hge2 = (h >= 2), hlt = (h < IMG_H - 2);

#pragma unroll
    for (int i = 0; i < 4; ++i) {
        float o[8];
        edge_core(r0[i + 2],
                  rm1[i], rm1[i + 1], rm1[i + 2],
                  r0[i + 1], r0[i + 3],
                  rp1[i], rp1[i + 1], rp1[i + 2],
                  r0[i],
                  rm2[i + 2],
                  rm2[i],
                  rp2[i],
                  o);
        int w = w0 + i;
        bool wge2 = (w >= 2), wlt = (w < IMG_W - 2);
        ov[0][i] = hge2           ? o[0] : 0.f;
        ov[1][i] = hlt            ? o[1] : 0.f;
        ov[2][i] = wge2           ? o[2] : 0.f;
        ov[3][i] = wlt            ? o[3] : 0.f;
        ov[4][i] = (hge2 && wge2) ? o[4] : 0.f;
        ov[5][i] = (hlt && wlt)   ? o[5] : 0.f;
        ov[6][i] = (hlt && wge2)  ? o[6] : 0.f;
        ov[7][i] = (hge2 && wlt)  ? o[7] : 0.f;
    }

    // ---- LDS-staged write phase: each wave owns one plane per phase ----
    // Block output region per plane: rows h0..h0+1 = 4KB contiguous.
    // Thread's float4 sits at byte offset tid*16 within that region
    // ((h-h0)*512 + w0 floats == tid*4 floats).
    __shared__ float4v lds[4][256];          // 16KB: 4 planes per phase

    const size_t cs = (size_t)IMG_H * IMG_W;
    float* oblk = out + ((size_t)n * 8) * cs + (size_t)h0 * IMG_W;
    int wave = tid >> 6;                     // 0..3: plane within phase
    int lane = tid & 63;

#pragma unroll
    for (int phase = 0; phase < 2; ++phase) {
        if (phase) __syncthreads();          // protect LDS reuse
#pragma unroll
        for (int j = 0; j < 4; ++j)
            lds[j][tid] = ov[phase * 4 + j];
        __syncthreads();
        int p = phase * 4 + wave;            // this wave's plane
        float* pdst = oblk + (size_t)p * cs;
#pragma unroll
        for (int c = 0; c < 4; ++c) {
            float4v v = lds[wave][c * 64 + lane];
            __builtin_nontemporal_store(
                v, (float4v*)(pdst + (size_t)(c * 64 + lane) * 4));
        }
    }
}

extern "C" void kernel_launch(void* const* d_in, const int* in_sizes, int n_in,
                              void* d_out, int out_size, void* d_ws, size_t ws_size,
                              hipStream_t stream) {
    const float* x = (const float*)d_in[0];
    float* out = (float*)d_out;
    int nimg = in_sizes[0] / (IMG_H * IMG_W);   // 48
    int grid = nimg * (IMG_H / 2);              // 12,288 blocks, exact
    edge_kernel<<<grid, 256, 0, stream>>>(x, out);
}